// Round 5
// baseline (1136.938 us; speedup 1.0000x reference)
//
#include <hip/hip_runtime.h>
#include <hip/hip_bf16.h>
#include <stdint.h>

#define DEV __device__ __forceinline__

typedef unsigned short u16;
typedef __bf16 bf16x8 __attribute__((ext_vector_type(8)));
typedef float f32x4 __attribute__((ext_vector_type(4)));

DEV float b2f(u16 u) { return __uint_as_float(((uint32_t)u) << 16); }
DEV u16 f2b(float f) {
  uint32_t u = __float_as_uint(f);
  u += 0x7fffu + ((u >> 16) & 1u);   // RNE
  return (u16)(u >> 16);
}
DEV float sigm(float z) { return __builtin_amdgcn_rcpf(1.f + __expf(-z)); }

// async global->LDS 16B. LDS dest is wave-uniform base + lane*16.
DEV void async16(const void* g, void* l) {
  __builtin_amdgcn_global_load_lds(
      (const __attribute__((address_space(1))) uint32_t*)g,
      (__attribute__((address_space(3))) uint32_t*)l, 16, 0, 0);
}

// ---------------- fused weight prep for all 4 layers + wout ----------------
// blocks [0,768) L1, [768,1536) L2, [1536,2048) L3, [2048,2432) L4, [2432,2464) wout.
// W'[k][c]=g[k]*W[k][c]; store W'^T at permuted col (d,j,h planes);
// scol=sum_k g*W, tcol=sum_k beta*W + SRU bias (bf for j==1, br for j==2).
__global__ __launch_bounds__(256) void prep_all_kernel(
    const float* __restrict__ W0, const float* __restrict__ W1,
    const float* __restrict__ W2, const float* __restrict__ W3,
    const float* __restrict__ g0, const float* __restrict__ g1,
    const float* __restrict__ g2, const float* __restrict__ g3,
    const float* __restrict__ b0, const float* __restrict__ b1,
    const float* __restrict__ b2, const float* __restrict__ b3,
    const float* __restrict__ sb0, const float* __restrict__ sb1,
    const float* __restrict__ sb2, const float* __restrict__ sb3,
    const float* __restrict__ wout,
    u16* __restrict__ Wt0, u16* __restrict__ Wt1, u16* __restrict__ Wt2,
    u16* __restrict__ Wt3,
    float* __restrict__ Sc0, float* __restrict__ Sc1, float* __restrict__ Sc2,
    float* __restrict__ Sc3,
    float* __restrict__ Tc0, float* __restrict__ Tc1, float* __restrict__ Tc2,
    float* __restrict__ Tc3,
    u16* __restrict__ wob) {
  int b = blockIdx.x;
  if (b >= 2432) {  // wout: 64*128 = 8192 elems
    int i = (b - 2432) * 256 + threadIdx.x;
    wob[i] = f2b(wout[i]);
    return;
  }
  const float *W, *g, *bv, *sb;
  u16* Wt;
  float *scol, *tcol;
  int K, hid, kk, c;
  if (b < 768) {
    W = W0; g = g0; bv = b0; sb = sb0; Wt = Wt0; scol = Sc0; tcol = Tc0;
    K = 256; hid = 128; kk = 3; c = b;
  } else if (b < 1536) {
    W = W1; g = g1; bv = b1; sb = sb1; Wt = Wt1; scol = Sc1; tcol = Tc1;
    K = 256; hid = 128; kk = 3; c = b - 768;
  } else if (b < 2048) {
    W = W2; g = g2; bv = b2; sb = sb2; Wt = Wt2; scol = Sc2; tcol = Tc2;
    K = 256; hid = 64; kk = 4; c = b - 1536;
  } else {
    W = W3; g = g3; bv = b3; sb = sb3; Wt = Wt3; scol = Sc3; tcol = Tc3;
    K = 128; hid = 64; kk = 3; c = b - 2048;
  }
  int C = 2 * hid * kk;
  int d = c / (hid * kk);
  int rem = c - d * hid * kk;
  int h = rem / kk;
  int j = rem - h * kk;
  int cp = (d * kk + j) * hid + h;  // permuted col: planes (d, j, h)

  int k2 = threadIdx.x;
  float a = 0.f, t = 0.f;
  if (k2 < K) {
    float w = W[(long long)k2 * C + c];
    float gg = g[k2];
    a = gg * w;
    t = bv[k2] * w;
    Wt[(long long)cp * K + k2] = f2b(a);
  }
#pragma unroll
  for (int off = 32; off; off >>= 1) { a += __shfl_xor(a, off); t += __shfl_xor(t, off); }
  __shared__ float sa[4], stt[4];
  int wv = threadIdx.x >> 6, ln = threadIdx.x & 63;
  if (ln == 0 && k2 < K) { sa[wv] = a; stt[wv] = t; }
  __syncthreads();
  if (threadIdx.x == 0) {
    float A = 0.f, T = 0.f;
    int nw = K >> 6;
    for (int i = 0; i < nw; ++i) { A += sa[i]; T += stt[i]; }
    float badd = 0.f;
    if (j == 1) badd = sb[2 * (d * hid + h)];
    else if (j == 2) badd = sb[2 * (d * hid + h) + 1];
    scol[cp] = A;
    tcol[cp] = T + badd;
  }
}

// ---------------- embedding + LN(ng,nb) -> bf16, (n,t) row layout ----------------
__global__ __launch_bounds__(256) void emb_kernel(const int* __restrict__ x,
                                                  const float* __restrict__ emb,
                                                  const float* __restrict__ ng,
                                                  const float* __restrict__ nb,
                                                  u16* __restrict__ out) {
  int row = blockIdx.x * 4 + (threadIdx.x >> 6);  // row = n*512 + t
  int lane = threadIdx.x & 63;
  int tok = x[(row & 511) * 256 + (row >> 9)];    // x is (t, n)
  float4 v = *(const float4*)&emb[(long long)tok * 256 + lane * 4];
  float s = v.x + v.y + v.z + v.w;
  float sq = v.x * v.x + v.y * v.y + v.z * v.z + v.w * v.w;
#pragma unroll
  for (int off = 32; off; off >>= 1) { s += __shfl_xor(s, off); sq += __shfl_xor(sq, off); }
  float m = s * (1.f / 256.f);
  float var = fmaxf(sq * (1.f / 256.f) - m * m, 0.f);
  float rstd = rsqrtf(var + 1e-5f);
  float4 g = *(const float4*)&ng[lane * 4];
  float4 b = *(const float4*)&nb[lane * 4];
  ushort4 o;
  o.x = f2b((v.x - m) * rstd * g.x + b.x);
  o.y = f2b((v.y - m) * rstd * g.y + b.y);
  o.z = f2b((v.z - m) * rstd * g.z + b.z);
  o.w = f2b((v.w - m) * rstd * g.w + b.w);
  *(ushort4*)&out[(long long)row * 256 + lane * 4] = o;
}

// ---------------- GEMM with fragment-derived row-stats ----------------
// U = rstd*(X@W') - m*rstd*scol + tcol, bf16 out.
// X: M x K bf16, Wt: C x K bf16 (B^T), tiles 128x128, BK=64, 4 waves.
// Row mean/rstd accumulated from A-fragments by wc==0 waves (no extra LDS reads).
__global__ __launch_bounds__(256) void gemm_kernel(const u16* __restrict__ X,
                                                   const u16* __restrict__ Wt,
                                                   float* __restrict__ statsOut,
                                                   const float* __restrict__ scol,
                                                   const float* __restrict__ tcol,
                                                   u16* __restrict__ U, int K, int C) {
  __shared__ u16 As[128 * 64];
  __shared__ u16 Bs[128 * 64];
  __shared__ float sm[128], sv[128];
  const int tid = threadIdx.x;
  const int lane = tid & 63, wid = tid >> 6;
  const int la = lane & 15, lq = lane >> 4;
  const int wr = wid >> 1, wc = wid & 1;
  const long long m0 = (long long)blockIdx.x * 128;
  const int c0 = blockIdx.y * 128;

  f32x4 acc[4][4] = {};
  float ssum[4] = {}, ssq[4] = {};
  const int nkt = K >> 6;
  const int rsb = K * 2;  // row stride bytes

  for (int kt = 0; kt < nkt; ++kt) {
    const char* abase = (const char*)X + (m0 * K + kt * 64) * 2;
    const char* bbase = (const char*)Wt + ((long long)c0 * K + kt * 64) * 2;
#pragma unroll
    for (int it = 0; it < 4; ++it) {
      int u = it * 256 + tid;
      int row = u >> 3, q = u & 7;
      int sq_ = (q ^ (row & 7)) << 4;
      async16(abase + (long long)row * rsb + sq_, (char*)As + it * 4096 + wid * 1024);
      async16(bbase + (long long)row * rsb + sq_, (char*)Bs + it * 4096 + wid * 1024);
    }
    __syncthreads();
#pragma unroll
    for (int ks = 0; ks < 2; ++ks) {
      bf16x8 a[4], b[4];
#pragma unroll
      for (int mf = 0; mf < 4; ++mf) {
        int row = wr * 64 + mf * 16 + la;
        a[mf] = *(const bf16x8*)&As[row * 64 + ((((ks << 2) | lq) ^ (row & 7)) << 3)];
      }
#pragma unroll
      for (int nf = 0; nf < 4; ++nf) {
        int row = wc * 64 + nf * 16 + la;
        b[nf] = *(const bf16x8*)&Bs[row * 64 + ((((ks << 2) | lq) ^ (row & 7)) << 3)];
      }
      if (wc == 0) {
        // lane holds granules {lq, lq+4} of row wr*64+mf*16+la in this k-tile
#pragma unroll
        for (int mf = 0; mf < 4; ++mf)
#pragma unroll
          for (int e = 0; e < 8; ++e) {
            float f = (float)a[mf][e];
            ssum[mf] += f;
            ssq[mf] = fmaf(f, f, ssq[mf]);
          }
      }
#pragma unroll
      for (int mf = 0; mf < 4; ++mf)
#pragma unroll
        for (int nf = 0; nf < 4; ++nf)
          acc[mf][nf] = __builtin_amdgcn_mfma_f32_16x16x32_bf16(a[mf], b[nf], acc[mf][nf], 0, 0, 0);
    }
    __syncthreads();
  }

  if (wc == 0) {
    float rk = 1.f / (float)K;
#pragma unroll
    for (int mf = 0; mf < 4; ++mf) {
      float s1 = ssum[mf], s2 = ssq[mf];
      s1 += __shfl_xor(s1, 16); s2 += __shfl_xor(s2, 16);
      s1 += __shfl_xor(s1, 32); s2 += __shfl_xor(s2, 32);
      if (lq == 0) {
        int row = wr * 64 + mf * 16 + la;
        float m = s1 * rk;
        float var = fmaxf(s2 * rk - m * m, 0.f);
        float rs = rsqrtf(var + 1e-5f);
        sm[row] = m;
        sv[row] = rs;
        if (blockIdx.y == 0) ((float2*)statsOut)[m0 + row] = make_float2(m, rs);
      }
    }
  }
  __syncthreads();

#pragma unroll
  for (int mf = 0; mf < 4; ++mf) {
    int lr0 = wr * 64 + mf * 16 + lq * 4;
    long long r0 = m0 + lr0;
#pragma unroll
    for (int nf = 0; nf < 4; ++nf) {
      int colg = c0 + wc * 64 + nf * 16 + la;
      float sc = scol[colg], tc = tcol[colg];
#pragma unroll
      for (int reg = 0; reg < 4; ++reg) {
        float uv = sv[lr0 + reg] * acc[mf][nf][reg] - sm[lr0 + reg] * sv[lr0 + reg] * sc + tc;
        U[(r0 + reg) * C + colg] = f2b(uv);
      }
    }
  }
}

// ---------------- SRU scan, LDS-staged ----------------
// (n,t) layout. One n per block, TPB = 2*HID threads (1 thread/chain).
// Per 8-step group: cooperative async16 staging of U rows (both directions,
// contiguous 8-row blocks; d=1 indexed reversed), double-buffered.
template <int KK, int LOGH>
__global__ __launch_bounds__(256) void scan_kernel(const u16* __restrict__ Uc,
                                                   const u16* __restrict__ X,
                                                   const float* __restrict__ stats,
                                                   const float* __restrict__ gln,
                                                   const float* __restrict__ bln,
                                                   const float* __restrict__ vv,
                                                   u16* __restrict__ H, int n0) {
  constexpr int T = 512;
  constexpr int HID = 1 << LOGH;
  constexpr int C = 2 * KK * HID;  // u16 per U row
  constexpr int DO = 2 * HID;
  constexpr int CH = 8;
  constexpr int TPB = 2 * HID;
  constexpr int RB = C * 2;                 // U row bytes
  constexpr int PD = CH * RB / 16 / TPB;    // U async16 per dir per thread

  __shared__ __align__(16) u16 Us[2][2][CH][C];
  __shared__ __align__(16) u16 Xs[2][2][CH][(KK == 3) ? DO : 8];
  __shared__ float2 Ss[2][2][CH];

  const int tid = threadIdx.x;
  const int h = tid & (HID - 1);
  const int d = tid >> LOGH;
  const int n = n0 + blockIdx.x;
  const char* Ub = (const char*)Uc + (size_t)blockIdx.x * T * RB;
  const char* Xb = (const char*)X + (size_t)n * T * DO * 2;
  const float2* Sb = (const float2*)stats + (size_t)n * T;
  u16* Hb = H + (size_t)n * T * DO + d * HID + h;

  const int col = d * HID + h;
  const float vf = vv[2 * col], vr = vv[2 * col + 1];
  float gc = 0.f, bc = 0.f;
  if (KK == 3) { gc = gln[col]; bc = bln[col]; }

  auto stage = [&](int g, int buf) {
    const int s = g * CH;
    const char* s0 = Ub + (size_t)s * RB;
    const char* s1 = Ub + (size_t)(T - CH - s) * RB;
    char* d0 = (char*)&Us[buf][0][0][0];
    char* d1 = (char*)&Us[buf][1][0][0];
#pragma unroll
    for (int it = 0; it < PD; ++it) {
      int o = (it * TPB + tid) * 16;
      async16(s0 + o, d0 + o);
      async16(s1 + o, d1 + o);
    }
    if (KK == 3) {
      int o = tid * 16;  // TPB*16 == CH*DO*2 exactly
      async16(Xb + (size_t)s * DO * 2 + o, (char*)&Xs[buf][0][0][0] + o);
      async16(Xb + (size_t)(T - CH - s) * DO * 2 + o, (char*)&Xs[buf][1][0][0] + o);
      if (tid < 2 * CH) {
        int dd = tid >> 3, i = tid & 7;
        Ss[buf][dd][i] = Sb[dd ? (T - CH - s + i) : (s + i)];
      }
    }
  };

  float c = 0.f;
  stage(0, 0);
  __syncthreads();
  for (int g = 0; g < T / CH; ++g) {
    int buf = g & 1;
    if (g + 1 < T / CH) stage(g + 1, buf ^ 1);
    const int s = g * CH;
#pragma unroll
    for (int i = 0; i < CH; ++i) {
      int jr = d ? (CH - 1 - i) : i;  // dir-1 rows stored ascending-t, read reversed
      const u16* ur = &Us[buf][d][jr][d * (KK * HID)];
      float xt = b2f(ur[h]);
      float fk = b2f(ur[HID + h]);
      float rk = b2f(ur[2 * HID + h]);
      float res;
      if (KK == 4) {
        res = b2f(ur[3 * HID + h]);
      } else {
        float xs = b2f(Xs[buf][d][jr][d * HID + h]);
        float2 st = Ss[buf][d][jr];
        res = (xs - st.x) * st.y * gc + bc;
      }
      float f = sigm(fma(vf, c, fk));
      float c2 = fma(f, c - xt, xt);
      float r = sigm(fma(vr, c, rk));
      float hh = fma(r, fmaxf(c2, 0.f) - res, res);
      c = c2;
      int t = d ? (T - 1 - (s + i)) : (s + i);
      Hb[(size_t)t * DO] = f2b(hh);
    }
    __syncthreads();
  }
}

// ---------------- final projection: out[r, :] = h4[r, :] @ wout^T + bout (f32 out) ------
// (n,t) layout makes h4 rows == out rows. M=131072, K=128, N=64.
__global__ __launch_bounds__(256) void outgemm_kernel(const u16* __restrict__ h4,
                                                      const u16* __restrict__ wob,
                                                      const float* __restrict__ bout,
                                                      float* __restrict__ out) {
  __shared__ u16 As[128 * 128];  // 32 KiB
  int tid = threadIdx.x;
  int lane = tid & 63, wid = tid >> 6;
  int la = lane & 15, lq = lane >> 4;
  long long m0 = (long long)blockIdx.x * 128;

#pragma unroll
  for (int it = 0; it < 8; ++it) {
    int u = it * 256 + tid;
    int row = u >> 4, q = u & 15;
    const char* src = (const char*)h4 + (m0 + row) * 256 + ((q ^ (row & 7)) << 4);
    async16(src, (char*)As + it * 4096 + wid * 1024);
  }
  bf16x8 bfr[4][4];
#pragma unroll
  for (int nf = 0; nf < 4; ++nf)
#pragma unroll
    for (int ks = 0; ks < 4; ++ks)
      bfr[nf][ks] = *(const bf16x8*)&wob[(nf * 16 + la) * 128 + ks * 32 + lq * 8];
  __syncthreads();

  f32x4 acc[2][4] = {};
#pragma unroll
  for (int ks = 0; ks < 4; ++ks) {
#pragma unroll
    for (int mf = 0; mf < 2; ++mf) {
      int row = wid * 32 + mf * 16 + la;
      bf16x8 a = *(const bf16x8*)&As[row * 128 + (((ks * 4 + lq) ^ (row & 7)) << 3)];
#pragma unroll
      for (int nf = 0; nf < 4; ++nf)
        acc[mf][nf] = __builtin_amdgcn_mfma_f32_16x16x32_bf16(a, bfr[nf][ks], acc[mf][nf], 0, 0, 0);
    }
  }
#pragma unroll
  for (int mf = 0; mf < 2; ++mf)
#pragma unroll
    for (int nf = 0; nf < 4; ++nf) {
      int colg = nf * 16 + la;
      float bo = bout[colg];
#pragma unroll
      for (int reg = 0; reg < 4; ++reg) {
        long long r = m0 + wid * 32 + mf * 16 + lq * 4 + reg;
        out[r * 64 + colg] = acc[mf][nf][reg] + bo;
      }
    }
}

// ---------------- launch ----------------
extern "C" void kernel_launch(void* const* d_in, const int* in_sizes, int n_in,
                              void* d_out, int out_size, void* d_ws, size_t ws_size,
                              hipStream_t stream) {
  const int* x = (const int*)d_in[0];
  const float* emb = (const float*)d_in[1];
  const float* ng = (const float*)d_in[2];
  const float* nb = (const float*)d_in[3];
  const float* W[4] = {(const float*)d_in[4], (const float*)d_in[9], (const float*)d_in[14],
                       (const float*)d_in[19]};
  const float* Vv[4] = {(const float*)d_in[5], (const float*)d_in[10], (const float*)d_in[15],
                        (const float*)d_in[20]};
  const float* Bv[4] = {(const float*)d_in[6], (const float*)d_in[11], (const float*)d_in[16],
                        (const float*)d_in[21]};
  const float* G[4] = {(const float*)d_in[7], (const float*)d_in[12], (const float*)d_in[17],
                       (const float*)d_in[22]};
  const float* Bt[4] = {(const float*)d_in[8], (const float*)d_in[13], (const float*)d_in[18],
                        (const float*)d_in[23]};
  const float* wout = (const float*)d_in[24];
  const float* bout = (const float*)d_in[25];
  float* out = (float*)d_out;

  char* ws = (char*)d_ws;
  u16* XA = (u16*)ws;                       // 64 MiB ping
  u16* XB = (u16*)(ws + 67108864);          // 64 MiB pong
  float* stats = (float*)(ws + 134217728);  // 1 MiB
  char* p = ws + 135266304;
  u16* Wt[4];
  float* Sc[4];
  float* Tc[4];
  int Kd[4] = {256, 256, 256, 128};
  int Hd[4] = {128, 128, 64, 64};
  int kkv[4] = {3, 3, 4, 3};
  for (int i = 0; i < 4; ++i) {
    int C = 2 * Hd[i] * kkv[i];
    Wt[i] = (u16*)p; p += (size_t)C * Kd[i] * 2;
    Sc[i] = (float*)p; p += (size_t)C * 4;
    Tc[i] = (float*)p; p += (size_t)C * 4;
  }
  u16* wob = (u16*)p;                       // 16 KiB; ends < 137363456
  u16* Ubuf = (u16*)(ws + 137363456);

  // largest n-chunk NC (rows = NC*512, max C = 768) that fits in ws_size; cap 256.
  int NC = 256;
  while (NC > 4 &&
         137363456ull + (unsigned long long)NC * 512 * 768 * 2 > (unsigned long long)ws_size)
    NC >>= 1;

  prep_all_kernel<<<dim3(2464), dim3(256), 0, stream>>>(
      W[0], W[1], W[2], W[3], G[0], G[1], G[2], G[3], Bt[0], Bt[1], Bt[2], Bt[3],
      Bv[0], Bv[1], Bv[2], Bv[3], wout,
      Wt[0], Wt[1], Wt[2], Wt[3], Sc[0], Sc[1], Sc[2], Sc[3], Tc[0], Tc[1], Tc[2], Tc[3],
      wob);
  emb_kernel<<<dim3(32768), dim3(256), 0, stream>>>(x, emb, ng, nb, XA);

  // L1: XA -> XB  (K=256, C=768, HID=128, kk=3)
  for (int c = 0; c < 256; c += NC) {
    gemm_kernel<<<dim3(NC * 4, 6), dim3(256), 0, stream>>>(
        XA + (size_t)c * 512 * 256, Wt[0], stats + (size_t)c * 512 * 2, Sc[0], Tc[0], Ubuf, 256, 768);
    scan_kernel<3, 7><<<dim3(NC), dim3(256), 0, stream>>>(
        Ubuf, XA, stats, G[0], Bt[0], Vv[0], XB, c);
  }
  // L2: XB -> XA
  for (int c = 0; c < 256; c += NC) {
    gemm_kernel<<<dim3(NC * 4, 6), dim3(256), 0, stream>>>(
        XB + (size_t)c * 512 * 256, Wt[1], stats + (size_t)c * 512 * 2, Sc[1], Tc[1], Ubuf, 256, 768);
    scan_kernel<3, 7><<<dim3(NC), dim3(256), 0, stream>>>(
        Ubuf, XB, stats, G[1], Bt[1], Vv[1], XA, c);
  }
  // L3: XA -> XB  (K=256, C=512, HID=64, kk=4: res from U plane 3)
  for (int c = 0; c < 256; c += NC) {
    gemm_kernel<<<dim3(NC * 4, 4), dim3(256), 0, stream>>>(
        XA + (size_t)c * 512 * 256, Wt[2], stats + (size_t)c * 512 * 2, Sc[2], Tc[2], Ubuf, 256, 512);
    scan_kernel<4, 6><<<dim3(NC), dim3(128), 0, stream>>>(
        Ubuf, Ubuf, stats, G[2], Bt[2], Vv[2], XB, c);
  }
  // L4: XB -> XA  (K=128, C=384, HID=64, kk=3)
  for (int c = 0; c < 256; c += NC) {
    gemm_kernel<<<dim3(NC * 4, 3), dim3(256), 0, stream>>>(
        XB + (size_t)c * 512 * 128, Wt[3], stats + (size_t)c * 512 * 2, Sc[3], Tc[3], Ubuf, 128, 384);
    scan_kernel<3, 6><<<dim3(NC), dim3(128), 0, stream>>>(
        Ubuf, XB, stats, G[3], Bt[3], Vv[3], XA, c);
  }
  // output projection
  outgemm_kernel<<<dim3(1024), dim3(256), 0, stream>>>(XA, wob, bout, out);
}

// Round 7
// 893.926 us; speedup vs baseline: 1.2718x; 1.2718x over previous
//
#include <hip/hip_runtime.h>
#include <hip/hip_bf16.h>
#include <stdint.h>

#define DEV __device__ __forceinline__

typedef unsigned short u16;
typedef __bf16 bf16x8 __attribute__((ext_vector_type(8)));
typedef float f32x4 __attribute__((ext_vector_type(4)));

DEV float b2f(u16 u) { return __uint_as_float(((uint32_t)u) << 16); }
DEV u16 f2b(float f) {
  uint32_t u = __float_as_uint(f);
  u += 0x7fffu + ((u >> 16) & 1u);   // RNE
  return (u16)(u >> 16);
}
DEV float sigm(float z) { return __builtin_amdgcn_rcpf(1.f + __expf(-z)); }

// async global->LDS 16B. LDS dest is wave-uniform base + lane*16.
DEV void async16(const void* g, void* l) {
  __builtin_amdgcn_global_load_lds(
      (const __attribute__((address_space(1))) uint32_t*)g,
      (__attribute__((address_space(3))) uint32_t*)l, 16, 0, 0);
}

// ---------------- fused weight prep for all 4 layers + wout ----------------
// blocks [0,768) L1, [768,1536) L2, [1536,2048) L3, [2048,2432) L4, [2432,2464) wout.
// W'[k][c]=g[k]*W[k][c]; store W'^T at permuted col (d,j,h planes);
// scol=sum_k g*W, tcol=sum_k beta*W + SRU bias (bf for j==1, br for j==2).
__global__ __launch_bounds__(256) void prep_all_kernel(
    const float* __restrict__ W0, const float* __restrict__ W1,
    const float* __restrict__ W2, const float* __restrict__ W3,
    const float* __restrict__ g0, const float* __restrict__ g1,
    const float* __restrict__ g2, const float* __restrict__ g3,
    const float* __restrict__ b0, const float* __restrict__ b1,
    const float* __restrict__ b2, const float* __restrict__ b3,
    const float* __restrict__ sb0, const float* __restrict__ sb1,
    const float* __restrict__ sb2, const float* __restrict__ sb3,
    const float* __restrict__ wout,
    u16* __restrict__ Wt0, u16* __restrict__ Wt1, u16* __restrict__ Wt2,
    u16* __restrict__ Wt3,
    float* __restrict__ Sc0, float* __restrict__ Sc1, float* __restrict__ Sc2,
    float* __restrict__ Sc3,
    float* __restrict__ Tc0, float* __restrict__ Tc1, float* __restrict__ Tc2,
    float* __restrict__ Tc3,
    u16* __restrict__ wob) {
  int b = blockIdx.x;
  if (b >= 2432) {  // wout: 64*128 = 8192 elems
    int i = (b - 2432) * 256 + threadIdx.x;
    wob[i] = f2b(wout[i]);
    return;
  }
  const float *W, *g, *bv, *sb;
  u16* Wt;
  float *scol, *tcol;
  int K, hid, kk, c;
  if (b < 768) {
    W = W0; g = g0; bv = b0; sb = sb0; Wt = Wt0; scol = Sc0; tcol = Tc0;
    K = 256; hid = 128; kk = 3; c = b;
  } else if (b < 1536) {
    W = W1; g = g1; bv = b1; sb = sb1; Wt = Wt1; scol = Sc1; tcol = Tc1;
    K = 256; hid = 128; kk = 3; c = b - 768;
  } else if (b < 2048) {
    W = W2; g = g2; bv = b2; sb = sb2; Wt = Wt2; scol = Sc2; tcol = Tc2;
    K = 256; hid = 64; kk = 4; c = b - 1536;
  } else {
    W = W3; g = g3; bv = b3; sb = sb3; Wt = Wt3; scol = Sc3; tcol = Tc3;
    K = 128; hid = 64; kk = 3; c = b - 2048;
  }
  int C = 2 * hid * kk;
  int d = c / (hid * kk);
  int rem = c - d * hid * kk;
  int h = rem / kk;
  int j = rem - h * kk;
  int cp = (d * kk + j) * hid + h;  // permuted col: planes (d, j, h)

  int k2 = threadIdx.x;
  float a = 0.f, t = 0.f;
  if (k2 < K) {
    float w = W[(long long)k2 * C + c];
    float gg = g[k2];
    a = gg * w;
    t = bv[k2] * w;
    Wt[(long long)cp * K + k2] = f2b(a);
  }
#pragma unroll
  for (int off = 32; off; off >>= 1) { a += __shfl_xor(a, off); t += __shfl_xor(t, off); }
  __shared__ float sa[4], stt[4];
  int wv = threadIdx.x >> 6, ln = threadIdx.x & 63;
  if (ln == 0 && k2 < K) { sa[wv] = a; stt[wv] = t; }
  __syncthreads();
  if (threadIdx.x == 0) {
    float A = 0.f, T = 0.f;
    int nw = K >> 6;
    for (int i = 0; i < nw; ++i) { A += sa[i]; T += stt[i]; }
    float badd = 0.f;
    if (j == 1) badd = sb[2 * (d * hid + h)];
    else if (j == 2) badd = sb[2 * (d * hid + h) + 1];
    scol[cp] = A;
    tcol[cp] = T + badd;
  }
}

// ---------------- embedding + LN(ng,nb) -> bf16, (n,t) row layout ----------------
__global__ __launch_bounds__(256) void emb_kernel(const int* __restrict__ x,
                                                  const float* __restrict__ emb,
                                                  const float* __restrict__ ng,
                                                  const float* __restrict__ nb,
                                                  u16* __restrict__ out) {
  int row = blockIdx.x * 4 + (threadIdx.x >> 6);  // row = n*512 + t
  int lane = threadIdx.x & 63;
  int tok = x[(row & 511) * 256 + (row >> 9)];    // x is (t, n)
  float4 v = *(const float4*)&emb[(long long)tok * 256 + lane * 4];
  float s = v.x + v.y + v.z + v.w;
  float sq = v.x * v.x + v.y * v.y + v.z * v.z + v.w * v.w;
#pragma unroll
  for (int off = 32; off; off >>= 1) { s += __shfl_xor(s, off); sq += __shfl_xor(sq, off); }
  float m = s * (1.f / 256.f);
  float var = fmaxf(sq * (1.f / 256.f) - m * m, 0.f);
  float rstd = rsqrtf(var + 1e-5f);
  float4 g = *(const float4*)&ng[lane * 4];
  float4 b = *(const float4*)&nb[lane * 4];
  ushort4 o;
  o.x = f2b((v.x - m) * rstd * g.x + b.x);
  o.y = f2b((v.y - m) * rstd * g.y + b.y);
  o.z = f2b((v.z - m) * rstd * g.z + b.z);
  o.w = f2b((v.w - m) * rstd * g.w + b.w);
  *(ushort4*)&out[(long long)row * 256 + lane * 4] = o;
}

// ---------------- GEMM with fragment-derived row-stats ----------------
// U = rstd*(X@W') - m*rstd*scol + tcol, bf16 out.
// X: M x K bf16, Wt: C x K bf16 (B^T), tiles 128x128, BK=64, 4 waves.
// Row mean/rstd accumulated from A-fragments by wc==0 waves (no extra LDS reads).
__global__ __launch_bounds__(256) void gemm_kernel(const u16* __restrict__ X,
                                                   const u16* __restrict__ Wt,
                                                   float* __restrict__ statsOut,
                                                   const float* __restrict__ scol,
                                                   const float* __restrict__ tcol,
                                                   u16* __restrict__ U, int K, int C) {
  __shared__ u16 As[128 * 64];
  __shared__ u16 Bs[128 * 64];
  __shared__ float sm[128], sv[128];
  const int tid = threadIdx.x;
  const int lane = tid & 63, wid = tid >> 6;
  const int la = lane & 15, lq = lane >> 4;
  const int wr = wid >> 1, wc = wid & 1;
  const long long m0 = (long long)blockIdx.x * 128;
  const int c0 = blockIdx.y * 128;

  f32x4 acc[4][4] = {};
  float ssum[4] = {}, ssq[4] = {};
  const int nkt = K >> 6;
  const int rsb = K * 2;  // row stride bytes

  for (int kt = 0; kt < nkt; ++kt) {
    const char* abase = (const char*)X + (m0 * K + kt * 64) * 2;
    const char* bbase = (const char*)Wt + ((long long)c0 * K + kt * 64) * 2;
#pragma unroll
    for (int it = 0; it < 4; ++it) {
      int u = it * 256 + tid;
      int row = u >> 3, q = u & 7;
      int sq_ = (q ^ (row & 7)) << 4;
      async16(abase + (long long)row * rsb + sq_, (char*)As + it * 4096 + wid * 1024);
      async16(bbase + (long long)row * rsb + sq_, (char*)Bs + it * 4096 + wid * 1024);
    }
    __syncthreads();
#pragma unroll
    for (int ks = 0; ks < 2; ++ks) {
      bf16x8 a[4], b[4];
#pragma unroll
      for (int mf = 0; mf < 4; ++mf) {
        int row = wr * 64 + mf * 16 + la;
        a[mf] = *(const bf16x8*)&As[row * 64 + ((((ks << 2) | lq) ^ (row & 7)) << 3)];
      }
#pragma unroll
      for (int nf = 0; nf < 4; ++nf) {
        int row = wc * 64 + nf * 16 + la;
        b[nf] = *(const bf16x8*)&Bs[row * 64 + ((((ks << 2) | lq) ^ (row & 7)) << 3)];
      }
      if (wc == 0) {
        // lane holds granules {lq, lq+4} of row wr*64+mf*16+la in this k-tile
#pragma unroll
        for (int mf = 0; mf < 4; ++mf)
#pragma unroll
          for (int e = 0; e < 8; ++e) {
            float f = (float)a[mf][e];
            ssum[mf] += f;
            ssq[mf] = fmaf(f, f, ssq[mf]);
          }
      }
#pragma unroll
      for (int mf = 0; mf < 4; ++mf)
#pragma unroll
        for (int nf = 0; nf < 4; ++nf)
          acc[mf][nf] = __builtin_amdgcn_mfma_f32_16x16x32_bf16(a[mf], b[nf], acc[mf][nf], 0, 0, 0);
    }
    __syncthreads();
  }

  if (wc == 0) {
    float rk = 1.f / (float)K;
#pragma unroll
    for (int mf = 0; mf < 4; ++mf) {
      float s1 = ssum[mf], s2 = ssq[mf];
      s1 += __shfl_xor(s1, 16); s2 += __shfl_xor(s2, 16);
      s1 += __shfl_xor(s1, 32); s2 += __shfl_xor(s2, 32);
      if (lq == 0) {
        int row = wr * 64 + mf * 16 + la;
        float m = s1 * rk;
        float var = fmaxf(s2 * rk - m * m, 0.f);
        float rs = rsqrtf(var + 1e-5f);
        sm[row] = m;
        sv[row] = rs;
        if (blockIdx.y == 0) ((float2*)statsOut)[m0 + row] = make_float2(m, rs);
      }
    }
  }
  __syncthreads();

#pragma unroll
  for (int mf = 0; mf < 4; ++mf) {
    int lr0 = wr * 64 + mf * 16 + lq * 4;
    long long r0 = m0 + lr0;
#pragma unroll
    for (int nf = 0; nf < 4; ++nf) {
      int colg = c0 + wc * 64 + nf * 16 + la;
      float sc = scol[colg], tc = tcol[colg];
#pragma unroll
      for (int reg = 0; reg < 4; ++reg) {
        float uv = sv[lr0 + reg] * acc[mf][nf][reg] - sm[lr0 + reg] * sv[lr0 + reg] * sc + tc;
        U[(r0 + reg) * C + colg] = f2b(uv);
      }
    }
  }
}

// ---------------- SRU scan, register triple-buffer (prefetch distance 2) ----------------
// (n,t) layout. One n per block, TPB = 2*HID (1 thread/chain). Biases folded into U.
template <int KK, int LOGH>
__global__ __launch_bounds__(256) void scan_kernel(const u16* __restrict__ Uc,
                                                   const u16* __restrict__ X,
                                                   const float* __restrict__ stats,
                                                   const float* __restrict__ gln,
                                                   const float* __restrict__ bln,
                                                   const float* __restrict__ vv,
                                                   u16* __restrict__ H, int n0) {
  constexpr int T = 512;
  constexpr int HID = 1 << LOGH;
  constexpr int C = 2 * KK * HID;
  constexpr int DO = 2 * HID;
  constexpr int CH = 8;

  int tid = threadIdx.x;
  int h = tid & (HID - 1);
  int d = tid >> LOGH;
  int nloc = blockIdx.x;
  int n = n0 + nloc;
  int col = d * HID + h;

  float vf = vv[2 * col], vr = vv[2 * col + 1];
  float gc = 0.f, bc = 0.f;
  if (KK == 3) { gc = gln[col]; bc = bln[col]; }

  int t0 = d ? (T - 1) : 0;
  long long stp = d ? -1 : 1;
  long long ustr = stp * (long long)C;
  long long xstr = stp * (long long)DO;
  long long sstr = stp;

  const u16* Up = Uc + ((long long)nloc * T + t0) * C + d * (KK * HID) + h;
  const u16* Xp = X + ((long long)n * T + t0) * DO + col;
  const float2* Sp = (const float2*)stats + ((long long)n * T + t0);
  u16* Hp = H + ((long long)n * T + t0) * DO + col;

  u16 p0x[CH], p0f[CH], p0r[CH], p0s[CH];
  float p0m[CH], p0v[CH];
  u16 p1x[CH], p1f[CH], p1r[CH], p1s[CH];
  float p1m[CH], p1v[CH];
  u16 p2x[CH], p2f[CH], p2r[CH], p2s[CH];
  float p2m[CH], p2v[CH];
  float c = 0.f;

#define SCAN_LOAD(S, BX, BF, BR, BS, BM, BV)                        \
  {                                                                 \
    _Pragma("unroll") for (int i = 0; i < CH; ++i) {                \
      long long o = (long long)((S) + i) * ustr;                    \
      BX[i] = Up[o];                                                \
      BF[i] = Up[o + HID];                                          \
      BR[i] = Up[o + 2 * HID];                                      \
      if (KK == 4) {                                                \
        BS[i] = Up[o + 3 * HID];                                    \
      } else {                                                      \
        BS[i] = Xp[(long long)((S) + i) * xstr];                    \
        float2 stv = Sp[(long long)((S) + i) * sstr];               \
        BM[i] = stv.x;                                              \
        BV[i] = stv.y;                                              \
      }                                                             \
    }                                                               \
  }

#define SCAN_COMP(S, BX, BF, BR, BS, BM, BV)                        \
  {                                                                 \
    _Pragma("unroll") for (int i = 0; i < CH; ++i) {                \
      float xt = b2f(BX[i]), fr = b2f(BF[i]), rr = b2f(BR[i]);      \
      float res = (KK == 4) ? b2f(BS[i])                            \
                            : (b2f(BS[i]) - BM[i]) * BV[i] * gc + bc; \
      float ff = sigm(fmaf(vf, c, fr));                             \
      float c2 = fmaf(ff, c - xt, xt);                              \
      float rg = sigm(fmaf(vr, c, rr));                             \
      float hh = fmaf(rg, fmaxf(c2, 0.f) - res, res);               \
      c = c2;                                                       \
      Hp[(long long)((S) + i) * xstr] = f2b(hh);                    \
    }                                                               \
  }

  // groups g -> buffer g%3; prefetch distance 2.
  SCAN_LOAD(0, p0x, p0f, p0r, p0s, p0m, p0v);
  SCAN_LOAD(CH, p1x, p1f, p1r, p1s, p1m, p1v);
  int s = 0;
  for (int it = 0; it < 20; ++it) {
    SCAN_LOAD(s + 2 * CH, p2x, p2f, p2r, p2s, p2m, p2v);
    SCAN_COMP(s, p0x, p0f, p0r, p0s, p0m, p0v);
    s += CH;
    SCAN_LOAD(s + 2 * CH, p0x, p0f, p0r, p0s, p0m, p0v);
    SCAN_COMP(s, p1x, p1f, p1r, p1s, p1m, p1v);
    s += CH;
    SCAN_LOAD(s + 2 * CH, p1x, p1f, p1r, p1s, p1m, p1v);
    SCAN_COMP(s, p2x, p2f, p2r, p2s, p2m, p2v);
    s += CH;
  }
  // s = 480 (group 60); groups 60->p0, 61->p1 loaded; load 62->p2, 63->p0.
  SCAN_LOAD(s + 2 * CH, p2x, p2f, p2r, p2s, p2m, p2v);
  SCAN_COMP(s, p0x, p0f, p0r, p0s, p0m, p0v);
  s += CH;
  SCAN_LOAD(s + 2 * CH, p0x, p0f, p0r, p0s, p0m, p0v);
  SCAN_COMP(s, p1x, p1f, p1r, p1s, p1m, p1v);
  s += CH;
  SCAN_COMP(s, p2x, p2f, p2r, p2s, p2m, p2v);
  s += CH;
  SCAN_COMP(s, p0x, p0f, p0r, p0s, p0m, p0v);
#undef SCAN_LOAD
#undef SCAN_COMP
}

// ---------------- final projection: out[r, :] = h4[r, :] @ wout^T + bout (f32 out) ------
// (n,t) layout makes h4 rows == out rows. M=131072, K=128, N=64.
__global__ __launch_bounds__(256) void outgemm_kernel(const u16* __restrict__ h4,
                                                      const u16* __restrict__ wob,
                                                      const float* __restrict__ bout,
                                                      float* __restrict__ out) {
  __shared__ u16 As[128 * 128];  // 32 KiB
  int tid = threadIdx.x;
  int lane = tid & 63, wid = tid >> 6;
  int la = lane & 15, lq = lane >> 4;
  long long m0 = (long long)blockIdx.x * 128;

#pragma unroll
  for (int it = 0; it < 8; ++it) {
    int u = it * 256 + tid;
    int row = u >> 4, q = u & 15;
    const char* src = (const char*)h4 + (m0 + row) * 256 + ((q ^ (row & 7)) << 4);
    async16(src, (char*)As + it * 4096 + wid * 1024);
  }
  bf16x8 bfr[4][4];
#pragma unroll
  for (int nf = 0; nf < 4; ++nf)
#pragma unroll
    for (int ks = 0; ks < 4; ++ks)
      bfr[nf][ks] = *(const bf16x8*)&wob[(nf * 16 + la) * 128 + ks * 32 + lq * 8];
  __syncthreads();

  f32x4 acc[2][4] = {};
#pragma unroll
  for (int ks = 0; ks < 4; ++ks) {
#pragma unroll
    for (int mf = 0; mf < 2; ++mf) {
      int row = wid * 32 + mf * 16 + la;
      bf16x8 a = *(const bf16x8*)&As[row * 128 + (((ks * 4 + lq) ^ (row & 7)) << 3)];
#pragma unroll
      for (int nf = 0; nf < 4; ++nf)
        acc[mf][nf] = __builtin_amdgcn_mfma_f32_16x16x32_bf16(a, bfr[nf][ks], acc[mf][nf], 0, 0, 0);
    }
  }
#pragma unroll
  for (int mf = 0; mf < 2; ++mf)
#pragma unroll
    for (int nf = 0; nf < 4; ++nf) {
      int colg = nf * 16 + la;
      float bo = bout[colg];
#pragma unroll
      for (int reg = 0; reg < 4; ++reg) {
        long long r = m0 + wid * 32 + mf * 16 + lq * 4 + reg;
        out[r * 64 + colg] = acc[mf][nf][reg] + bo;
      }
    }
}

// ---------------- launch ----------------
extern "C" void kernel_launch(void* const* d_in, const int* in_sizes, int n_in,
                              void* d_out, int out_size, void* d_ws, size_t ws_size,
                              hipStream_t stream) {
  const int* x = (const int*)d_in[0];
  const float* emb = (const float*)d_in[1];
  const float* ng = (const float*)d_in[2];
  const float* nb = (const float*)d_in[3];
  const float* W[4] = {(const float*)d_in[4], (const float*)d_in[9], (const float*)d_in[14],
                       (const float*)d_in[19]};
  const float* Vv[4] = {(const float*)d_in[5], (const float*)d_in[10], (const float*)d_in[15],
                        (const float*)d_in[20]};
  const float* Bv[4] = {(const float*)d_in[6], (const float*)d_in[11], (const float*)d_in[16],
                        (const float*)d_in[21]};
  const float* G[4] = {(const float*)d_in[7], (const float*)d_in[12], (const float*)d_in[17],
                       (const float*)d_in[22]};
  const float* Bt[4] = {(const float*)d_in[8], (const float*)d_in[13], (const float*)d_in[18],
                        (const float*)d_in[23]};
  const float* wout = (const float*)d_in[24];
  const float* bout = (const float*)d_in[25];
  float* out = (float*)d_out;

  char* ws = (char*)d_ws;
  u16* XA = (u16*)ws;                       // 64 MiB ping
  u16* XB = (u16*)(ws + 67108864);          // 64 MiB pong
  float* stats = (float*)(ws + 134217728);  // 1 MiB
  char* p = ws + 135266304;
  u16* Wt[4];
  float* Sc[4];
  float* Tc[4];
  int Kd[4] = {256, 256, 256, 128};
  int Hd[4] = {128, 128, 64, 64};
  int kkv[4] = {3, 3, 4, 3};
  for (int i = 0; i < 4; ++i) {
    int C = 2 * Hd[i] * kkv[i];
    Wt[i] = (u16*)p; p += (size_t)C * Kd[i] * 2;
    Sc[i] = (float*)p; p += (size_t)C * 4;
    Tc[i] = (float*)p; p += (size_t)C * 4;
  }
  u16* wob = (u16*)p;                       // 16 KiB; ends < 137363456
  u16* Ubuf = (u16*)(ws + 137363456);

  // largest n-chunk NC (rows = NC*512, max C = 768) that fits in ws_size; cap 256.
  int NC = 256;
  while (NC > 4 &&
         137363456ull + (unsigned long long)NC * 512 * 768 * 2 > (unsigned long long)ws_size)
    NC >>= 1;

  prep_all_kernel<<<dim3(2464), dim3(256), 0, stream>>>(
      W[0], W[1], W[2], W[3], G[0], G[1], G[2], G[3], Bt[0], Bt[1], Bt[2], Bt[3],
      Bv[0], Bv[1], Bv[2], Bv[3], wout,
      Wt[0], Wt[1], Wt[2], Wt[3], Sc[0], Sc[1], Sc[2], Sc[3], Tc[0], Tc[1], Tc[2], Tc[3],
      wob);
  emb_kernel<<<dim3(32768), dim3(256), 0, stream>>>(x, emb, ng, nb, XA);

  // L1: XA -> XB  (K=256, C=768, HID=128, kk=3)
  for (int c = 0; c < 256; c += NC) {
    gemm_kernel<<<dim3(NC * 4, 6), dim3(256), 0, stream>>>(
        XA + (size_t)c * 512 * 256, Wt[0], stats + (size_t)c * 512 * 2, Sc[0], Tc[0], Ubuf, 256, 768);
    scan_kernel<3, 7><<<dim3(NC), dim3(256), 0, stream>>>(
        Ubuf, XA, stats, G[0], Bt[0], Vv[0], XB, c);
  }
  // L2: XB -> XA
  for (int c = 0; c < 256; c += NC) {
    gemm_kernel<<<dim3(NC * 4, 6), dim3(256), 0, stream>>>(
        XB + (size_t)c * 512 * 256, Wt[1], stats + (size_t)c * 512 * 2, Sc[1], Tc[1], Ubuf, 256, 768);
    scan_kernel<3, 7><<<dim3(NC), dim3(256), 0, stream>>>(
        Ubuf, XB, stats, G[1], Bt[1], Vv[1], XA, c);
  }
  // L3: XA -> XB  (K=256, C=512, HID=64, kk=4: res from U plane 3)
  for (int c = 0; c < 256; c += NC) {
    gemm_kernel<<<dim3(NC * 4, 4), dim3(256), 0, stream>>>(
        XA + (size_t)c * 512 * 256, Wt[2], stats + (size_t)c * 512 * 2, Sc[2], Tc[2], Ubuf, 256, 512);
    scan_kernel<4, 6><<<dim3(NC), dim3(128), 0, stream>>>(
        Ubuf, Ubuf, stats, G[2], Bt[2], Vv[2], XB, c);
  }
  // L4: XB -> XA  (K=128, C=384, HID=64, kk=3)
  for (int c = 0; c < 256; c += NC) {
    gemm_kernel<<<dim3(NC * 4, 3), dim3(256), 0, stream>>>(
        XB + (size_t)c * 512 * 128, Wt[3], stats + (size_t)c * 512 * 2, Sc[3], Tc[3], Ubuf, 128, 384);
    scan_kernel<3, 6><<<dim3(NC), dim3(128), 0, stream>>>(
        Ubuf, XB, stats, G[3], Bt[3], Vv[3], XA, c);
  }
  // output projection
  outgemm_kernel<<<dim3(1024), dim3(256), 0, stream>>>(XA, wob, bout, out);
}

// Round 8
// 707.871 us; speedup vs baseline: 1.6061x; 1.2628x over previous
//
#include <hip/hip_runtime.h>
#include <hip/hip_bf16.h>
#include <stdint.h>

#define DEV __device__ __forceinline__

typedef unsigned short u16;
typedef __bf16 bf16x8 __attribute__((ext_vector_type(8)));
typedef float f32x4 __attribute__((ext_vector_type(4)));

DEV float b2f(u16 u) { return __uint_as_float(((uint32_t)u) << 16); }
DEV u16 f2b(float f) {
  uint32_t u = __float_as_uint(f);
  u += 0x7fffu + ((u >> 16) & 1u);   // RNE
  return (u16)(u >> 16);
}
DEV float sigm(float z) { return __builtin_amdgcn_rcpf(1.f + __expf(-z)); }

// async global->LDS 16B. LDS dest is wave-uniform base + lane*16.
DEV void async16(const void* g, void* l) {
  __builtin_amdgcn_global_load_lds(
      (const __attribute__((address_space(1))) uint32_t*)g,
      (__attribute__((address_space(3))) uint32_t*)l, 16, 0, 0);
}

// ---------------- fused weight prep for all 4 layers + wout ----------------
// blocks [0,768) L1, [768,1536) L2, [1536,2048) L3, [2048,2432) L4, [2432,2464) wout.
// W'[k][c]=g[k]*W[k][c]; store W'^T at permuted col (d,j,h planes);
// scol=sum_k g*W, tcol=sum_k beta*W + SRU bias (bf for j==1, br for j==2).
__global__ __launch_bounds__(256) void prep_all_kernel(
    const float* __restrict__ W0, const float* __restrict__ W1,
    const float* __restrict__ W2, const float* __restrict__ W3,
    const float* __restrict__ g0, const float* __restrict__ g1,
    const float* __restrict__ g2, const float* __restrict__ g3,
    const float* __restrict__ b0, const float* __restrict__ b1,
    const float* __restrict__ b2, const float* __restrict__ b3,
    const float* __restrict__ sb0, const float* __restrict__ sb1,
    const float* __restrict__ sb2, const float* __restrict__ sb3,
    const float* __restrict__ wout,
    u16* __restrict__ Wt0, u16* __restrict__ Wt1, u16* __restrict__ Wt2,
    u16* __restrict__ Wt3,
    float* __restrict__ Sc0, float* __restrict__ Sc1, float* __restrict__ Sc2,
    float* __restrict__ Sc3,
    float* __restrict__ Tc0, float* __restrict__ Tc1, float* __restrict__ Tc2,
    float* __restrict__ Tc3,
    u16* __restrict__ wob) {
  int b = blockIdx.x;
  if (b >= 2432) {  // wout: 64*128 = 8192 elems
    int i = (b - 2432) * 256 + threadIdx.x;
    wob[i] = f2b(wout[i]);
    return;
  }
  const float *W, *g, *bv, *sb;
  u16* Wt;
  float *scol, *tcol;
  int K, hid, kk, c;
  if (b < 768) {
    W = W0; g = g0; bv = b0; sb = sb0; Wt = Wt0; scol = Sc0; tcol = Tc0;
    K = 256; hid = 128; kk = 3; c = b;
  } else if (b < 1536) {
    W = W1; g = g1; bv = b1; sb = sb1; Wt = Wt1; scol = Sc1; tcol = Tc1;
    K = 256; hid = 128; kk = 3; c = b - 768;
  } else if (b < 2048) {
    W = W2; g = g2; bv = b2; sb = sb2; Wt = Wt2; scol = Sc2; tcol = Tc2;
    K = 256; hid = 64; kk = 4; c = b - 1536;
  } else {
    W = W3; g = g3; bv = b3; sb = sb3; Wt = Wt3; scol = Sc3; tcol = Tc3;
    K = 128; hid = 64; kk = 3; c = b - 2048;
  }
  int C = 2 * hid * kk;
  int d = c / (hid * kk);
  int rem = c - d * hid * kk;
  int h = rem / kk;
  int j = rem - h * kk;
  int cp = (d * kk + j) * hid + h;  // permuted col: planes (d, j, h)

  int k2 = threadIdx.x;
  float a = 0.f, t = 0.f;
  if (k2 < K) {
    float w = W[(long long)k2 * C + c];
    float gg = g[k2];
    a = gg * w;
    t = bv[k2] * w;
    Wt[(long long)cp * K + k2] = f2b(a);
  }
#pragma unroll
  for (int off = 32; off; off >>= 1) { a += __shfl_xor(a, off); t += __shfl_xor(t, off); }
  __shared__ float sa[4], stt[4];
  int wv = threadIdx.x >> 6, ln = threadIdx.x & 63;
  if (ln == 0 && k2 < K) { sa[wv] = a; stt[wv] = t; }
  __syncthreads();
  if (threadIdx.x == 0) {
    float A = 0.f, T = 0.f;
    int nw = K >> 6;
    for (int i = 0; i < nw; ++i) { A += sa[i]; T += stt[i]; }
    float badd = 0.f;
    if (j == 1) badd = sb[2 * (d * hid + h)];
    else if (j == 2) badd = sb[2 * (d * hid + h) + 1];
    scol[cp] = A;
    tcol[cp] = T + badd;
  }
}

// ---------------- embedding + LN(ng,nb) -> bf16, (n,t) row layout ----------------
__global__ __launch_bounds__(256) void emb_kernel(const int* __restrict__ x,
                                                  const float* __restrict__ emb,
                                                  const float* __restrict__ ng,
                                                  const float* __restrict__ nb,
                                                  u16* __restrict__ out) {
  int row = blockIdx.x * 4 + (threadIdx.x >> 6);  // row = n*512 + t
  int lane = threadIdx.x & 63;
  int tok = x[(row & 511) * 256 + (row >> 9)];    // x is (t, n)
  float4 v = *(const float4*)&emb[(long long)tok * 256 + lane * 4];
  float s = v.x + v.y + v.z + v.w;
  float sq = v.x * v.x + v.y * v.y + v.z * v.z + v.w * v.w;
#pragma unroll
  for (int off = 32; off; off >>= 1) { s += __shfl_xor(s, off); sq += __shfl_xor(sq, off); }
  float m = s * (1.f / 256.f);
  float var = fmaxf(sq * (1.f / 256.f) - m * m, 0.f);
  float rstd = rsqrtf(var + 1e-5f);
  float4 g = *(const float4*)&ng[lane * 4];
  float4 b = *(const float4*)&nb[lane * 4];
  ushort4 o;
  o.x = f2b((v.x - m) * rstd * g.x + b.x);
  o.y = f2b((v.y - m) * rstd * g.y + b.y);
  o.z = f2b((v.z - m) * rstd * g.z + b.z);
  o.w = f2b((v.w - m) * rstd * g.w + b.w);
  *(ushort4*)&out[(long long)row * 256 + lane * 4] = o;
}

// ---------------- fused LN+GEMM+scan per layer ----------------
// One block per (n, dir): 512 threads. Waves 2..2+GW-1: GEMM (W_d in regs, B^T),
// waves 2,3 also stage X tiles (pre-swizzled src -> linear LDS). Waves 0-1: scan.
// Pipeline over 16 t-tiles of 32 steps; X triple-buffered, U/stat double-buffered.
template <int KK, int LOGH, int K, int GW, int MT>
__global__ __launch_bounds__(512, 2) void fused_layer_kernel(
    const u16* __restrict__ X, const u16* __restrict__ Wt,
    const float* __restrict__ scol, const float* __restrict__ tcol,
    const float* __restrict__ gln, const float* __restrict__ bln,
    const float* __restrict__ vv, u16* __restrict__ H) {
  constexpr int T = 512, TT = 32, NT = 16;
  constexpr int HID = 1 << LOGH;
  constexpr int DO = 2 * HID;
  constexpr int NC = KK * HID;   // U cols this direction
  constexpr int UP = NC + 8;     // padded row
  constexpr int KST = K / 32;
  constexpr int GR = K / 8;      // 16B granules per X row
  constexpr int SL = TT * GR;    // 16B slots per X tile
  static_assert(GW * MT * 16 == NC, "tile coverage");

  __shared__ u16 Xs[3][TT * GR * 8];
  __shared__ u16 Us[2][TT][UP];
  __shared__ float2 Sst[2][TT];

  const int tid = threadIdx.x;
  const int lane = tid & 63, wid = tid >> 6;
  const int la = lane & 15, lq = lane >> 4;
  const int d = blockIdx.x >> 8;
  const int n = blockIdx.x & 255;
  const int cp0 = d * NC;
  const size_t xr0 = (size_t)n * T;

  const bool is_scan = (tid < HID);
  const bool is_gemm = (wid >= 2 && wid < 2 + GW);
  const bool is_stage = (wid == 2 || wid == 3);

  // ---- GEMM persistent: B fragments + per-col scol/tcol ----
  bf16x8 Bf[MT][KST];
  float scv[MT], tcv[MT];
  const int nt0 = (wid - 2) * MT;
  if (is_gemm) {
#pragma unroll
    for (int j = 0; j < MT; ++j) {
      int cg = cp0 + (nt0 + j) * 16 + la;
      scv[j] = scol[cg];
      tcv[j] = tcol[cg];
#pragma unroll
      for (int kt = 0; kt < KST; ++kt)
        Bf[j][kt] = *(const bf16x8*)&Wt[(size_t)cg * K + kt * 32 + lq * 8];
    }
  }
  // ---- scan persistent ----
  float vf = 0.f, vr = 0.f, gc = 0.f, bc = 0.f, c = 0.f;
  int col = 0, pg = 0, pe = 0;
  if (is_scan) {
    col = d * HID + tid;
    vf = vv[2 * col];
    vr = vv[2 * col + 1];
    if (KK == 3) { gc = gln[col]; bc = bln[col]; }
    pg = col >> 3;
    pe = col & 7;
  }

#define STAGE_X(G)                                                          \
  {                                                                         \
    int b3_ = (G) % 3;                                                      \
    int rb_ = d ? (T - ((G) + 1) * TT) : (G) * TT;                          \
    const char* s0_ = (const char*)(X + (xr0 + rb_) * K);                   \
    char* dl_ = (char*)&Xs[b3_][0];                                         \
    int st_ = tid - 128;                                                    \
    _Pragma("unroll") for (int i_ = 0; i_ < SL / 128; ++i_) {               \
      int u_ = i_ * 128 + st_;                                              \
      int row_ = u_ / GR, q_ = u_ % GR;                                     \
      async16(s0_ + (size_t)row_ * (K * 2) + ((q_ ^ (row_ & 7)) << 4),      \
              dl_ + i_ * 2048 + (wid - 2) * 1024);                          \
    }                                                                       \
  }

  if (is_stage) STAGE_X(0);
  __syncthreads();

  for (int g = 0; g <= NT; ++g) {
    if (g < NT && is_gemm) {
      const int xb = g % 3;
      if (is_stage && g + 1 < NT) STAGE_X(g + 1);
      const u16* xp = &Xs[xb][0];
      // row stats (redundant per wave; lane pair (2r,2r+1) -> row r)
      const int srow = lane >> 1;
      const int h0 = (lane & 1) * (GR / 2);
      float s1 = 0.f, s2 = 0.f;
#pragma unroll
      for (int q = 0; q < GR / 2; ++q) {
        bf16x8 v = *(const bf16x8*)&xp[(srow * GR + h0 + (q ^ (srow & 7))) * 8];
#pragma unroll
        for (int e = 0; e < 8; ++e) {
          float f = (float)v[e];
          s1 += f;
          s2 = fmaf(f, f, s2);
        }
      }
      s1 += __shfl_xor(s1, 1);
      s2 += __shfl_xor(s2, 1);
      float mv = s1 * (1.f / (float)K);
      float rsv = rsqrtf(fmaxf(s2 * (1.f / (float)K) - mv * mv, 0.f) + 1e-5f);
      if (KK == 3 && wid == 2 && (lane & 1) == 0) Sst[g & 1][srow] = make_float2(mv, rsv);
      float mr[2][4], rrw[2][4];
#pragma unroll
      for (int mt = 0; mt < 2; ++mt)
#pragma unroll
        for (int rg = 0; rg < 4; ++rg) {
          int row = mt * 16 + lq * 4 + rg;
          mr[mt][rg] = __shfl(mv, row * 2);
          rrw[mt][rg] = __shfl(rsv, row * 2);
        }
      // MFMA
      f32x4 acc[2][MT] = {};
#pragma unroll
      for (int kt = 0; kt < KST; ++kt) {
        bf16x8 a0, a1;
        {
          int r0 = la;
          a0 = *(const bf16x8*)&xp[(r0 * GR + ((kt * 4 + lq) ^ (r0 & 7))) * 8];
          int r1 = 16 + la;
          a1 = *(const bf16x8*)&xp[(r1 * GR + ((kt * 4 + lq) ^ (r1 & 7))) * 8];
        }
#pragma unroll
        for (int j = 0; j < MT; ++j) {
          acc[0][j] = __builtin_amdgcn_mfma_f32_16x16x32_bf16(a0, Bf[j][kt], acc[0][j], 0, 0, 0);
          acc[1][j] = __builtin_amdgcn_mfma_f32_16x16x32_bf16(a1, Bf[j][kt], acc[1][j], 0, 0, 0);
        }
      }
      // epilogue: U = rs*acc - m*rs*scol + tcol -> LDS (bf16)
#pragma unroll
      for (int mt = 0; mt < 2; ++mt)
#pragma unroll
        for (int j = 0; j < MT; ++j)
#pragma unroll
          for (int rg = 0; rg < 4; ++rg) {
            int row = mt * 16 + lq * 4 + rg;
            float uv = rrw[mt][rg] * acc[mt][j][rg] - mr[mt][rg] * rrw[mt][rg] * scv[j] + tcv[j];
            Us[g & 1][row][(nt0 + j) * 16 + la] = f2b(uv);
          }
    }
    if (g >= 1 && is_scan) {
      const int tg = g - 1;
      const int xb = tg % 3, ub = tg & 1;
      const int rb = d ? (T - (tg + 1) * TT) : tg * TT;
      u16* Hb = H + (xr0 + rb) * DO + col;
      const u16* up = &Us[ub][0][0];
      const u16* xp = &Xs[xb][0];
#pragma unroll
      for (int stp = 0; stp < TT; ++stp) {
        int r = d ? (TT - 1 - stp) : stp;
        float xt = b2f(up[r * UP + tid]);
        float fk = b2f(up[r * UP + HID + tid]);
        float rk = b2f(up[r * UP + 2 * HID + tid]);
        float res;
        if (KK == 4) {
          res = b2f(up[r * UP + 3 * HID + tid]);
        } else {
          float xs = b2f(xp[(r * GR + (pg ^ (r & 7))) * 8 + pe]);
          float2 stv = Sst[ub][r];
          res = (xs - stv.x) * stv.y * gc + bc;
        }
        float f = sigm(fmaf(vf, c, fk));
        float c2 = fmaf(f, c - xt, xt);
        float rg2 = sigm(fmaf(vr, c, rk));
        float hh = fmaf(rg2, fmaxf(c2, 0.f) - res, res);
        c = c2;
        Hb[(size_t)r * DO] = f2b(hh);
      }
    }
    __syncthreads();
  }
#undef STAGE_X
}

// ---------------- final projection: out[r, :] = h4[r, :] @ wout^T + bout (f32 out) ------
__global__ __launch_bounds__(256) void outgemm_kernel(const u16* __restrict__ h4,
                                                      const u16* __restrict__ wob,
                                                      const float* __restrict__ bout,
                                                      float* __restrict__ out) {
  __shared__ u16 As[128 * 128];  // 32 KiB
  int tid = threadIdx.x;
  int lane = tid & 63, wid = tid >> 6;
  int la = lane & 15, lq = lane >> 4;
  long long m0 = (long long)blockIdx.x * 128;

#pragma unroll
  for (int it = 0; it < 8; ++it) {
    int u = it * 256 + tid;
    int row = u >> 4, q = u & 15;
    const char* src = (const char*)h4 + (m0 + row) * 256 + ((q ^ (row & 7)) << 4);
    async16(src, (char*)As + it * 4096 + wid * 1024);
  }
  bf16x8 bfr[4][4];
#pragma unroll
  for (int nf = 0; nf < 4; ++nf)
#pragma unroll
    for (int ks = 0; ks < 4; ++ks)
      bfr[nf][ks] = *(const bf16x8*)&wob[(nf * 16 + la) * 128 + ks * 32 + lq * 8];
  __syncthreads();

  f32x4 acc[2][4] = {};
#pragma unroll
  for (int ks = 0; ks < 4; ++ks) {
#pragma unroll
    for (int mf = 0; mf < 2; ++mf) {
      int row = wid * 32 + mf * 16 + la;
      bf16x8 a = *(const bf16x8*)&As[row * 128 + (((ks * 4 + lq) ^ (row & 7)) << 3)];
#pragma unroll
      for (int nf = 0; nf < 4; ++nf)
        acc[mf][nf] = __builtin_amdgcn_mfma_f32_16x16x32_bf16(a, bfr[nf][ks], acc[mf][nf], 0, 0, 0);
    }
  }
#pragma unroll
  for (int mf = 0; mf < 2; ++mf)
#pragma unroll
    for (int nf = 0; nf < 4; ++nf) {
      int colg = nf * 16 + la;
      float bo = bout[colg];
#pragma unroll
      for (int reg = 0; reg < 4; ++reg) {
        long long r = m0 + wid * 32 + mf * 16 + lq * 4 + reg;
        out[r * 64 + colg] = acc[mf][nf][reg] + bo;
      }
    }
}

// ---------------- launch ----------------
extern "C" void kernel_launch(void* const* d_in, const int* in_sizes, int n_in,
                              void* d_out, int out_size, void* d_ws, size_t ws_size,
                              hipStream_t stream) {
  const int* x = (const int*)d_in[0];
  const float* emb = (const float*)d_in[1];
  const float* ng = (const float*)d_in[2];
  const float* nb = (const float*)d_in[3];
  const float* W[4] = {(const float*)d_in[4], (const float*)d_in[9], (const float*)d_in[14],
                       (const float*)d_in[19]};
  const float* Vv[4] = {(const float*)d_in[5], (const float*)d_in[10], (const float*)d_in[15],
                        (const float*)d_in[20]};
  const float* Bv[4] = {(const float*)d_in[6], (const float*)d_in[11], (const float*)d_in[16],
                        (const float*)d_in[21]};
  const float* G[4] = {(const float*)d_in[7], (const float*)d_in[12], (const float*)d_in[17],
                       (const float*)d_in[22]};
  const float* Bt[4] = {(const float*)d_in[8], (const float*)d_in[13], (const float*)d_in[18],
                        (const float*)d_in[23]};
  const float* wout = (const float*)d_in[24];
  const float* bout = (const float*)d_in[25];
  float* out = (float*)d_out;

  char* ws = (char*)d_ws;
  u16* XA = (u16*)ws;                       // 64 MiB ping
  u16* XB = (u16*)(ws + 67108864);          // 64 MiB pong
  char* p = ws + 134217728;
  u16* Wt[4];
  float* Sc[4];
  float* Tc[4];
  int Kd[4] = {256, 256, 256, 128};
  int Hd[4] = {128, 128, 64, 64};
  int kkv[4] = {3, 3, 4, 3};
  for (int i = 0; i < 4; ++i) {
    int C = 2 * Hd[i] * kkv[i];
    Wt[i] = (u16*)p; p += (size_t)C * Kd[i] * 2;
    Sc[i] = (float*)p; p += (size_t)C * 4;
    Tc[i] = (float*)p; p += (size_t)C * 4;
  }
  u16* wob = (u16*)p;

  prep_all_kernel<<<dim3(2464), dim3(256), 0, stream>>>(
      W[0], W[1], W[2], W[3], G[0], G[1], G[2], G[3], Bt[0], Bt[1], Bt[2], Bt[3],
      Bv[0], Bv[1], Bv[2], Bv[3], wout,
      Wt[0], Wt[1], Wt[2], Wt[3], Sc[0], Sc[1], Sc[2], Sc[3], Tc[0], Tc[1], Tc[2], Tc[3],
      wob);
  emb_kernel<<<dim3(32768), dim3(256), 0, stream>>>(x, emb, ng, nb, XA);

  // L1: XA -> XB  (K=256, HID=128, kk=3): NC=384=6 waves*4 tiles
  fused_layer_kernel<3, 7, 256, 6, 4><<<dim3(512), dim3(512), 0, stream>>>(
      XA, Wt[0], Sc[0], Tc[0], G[0], Bt[0], Vv[0], XB);
  // L2: XB -> XA
  fused_layer_kernel<3, 7, 256, 6, 4><<<dim3(512), dim3(512), 0, stream>>>(
      XB, Wt[1], Sc[1], Tc[1], G[1], Bt[1], Vv[1], XA);
  // L3: XA -> XB  (K=256, HID=64, kk=4): NC=256=4 waves*4 tiles
  fused_layer_kernel<4, 6, 256, 4, 4><<<dim3(512), dim3(512), 0, stream>>>(
      XA, Wt[2], Sc[2], Tc[2], G[2], Bt[2], Vv[2], XB);
  // L4: XB -> XA  (K=128, HID=64, kk=3): NC=192=6 waves*2 tiles
  fused_layer_kernel<3, 6, 128, 6, 2><<<dim3(512), dim3(512), 0, stream>>>(
      XB, Wt[3], Sc[3], Tc[3], G[3], Bt[3], Vv[3], XA);
  // output projection
  outgemm_kernel<<<dim3(1024), dim3(256), 0, stream>>>(XA, wob, bout, out);
}